// Round 6
// baseline (73.018 us; speedup 1.0000x reference)
//
#include <hip/hip_runtime.h>
#include <math.h>

#define FAR_DELTA 1e10f

// One wave (64 lanes) per ray. Lane i owns samples i and i+64 of N=128.
// f32 inputs, f32 outputs.
//
// KEY NUMERICS FIX: the last sample's tau = density*1e10 is ~1e9-1e10.
// The reference's cumsum never includes it (cumsum over tau[:-1]).
// Scanning it and subtracting back loses the small prefix (ulp(1e9)=64),
// inflating the last sample's weight by e^{sum of lost taus}. So we scan
// u_b = (lane==63 ? 0 : tau_b) — the huge tau only ever appears in its
// own (1 - exp(-tau)) factor, never inside the scan.
__global__ __launch_bounds__(256) void volrend_kernel(
    const float* __restrict__ density,   // (B,128,1) f32
    const float* __restrict__ feature,   // (B,128,3) f32
    const float* __restrict__ depth,     // (B,128)   f32
    float* __restrict__ feat_out,        // (B,3) f32
    float* __restrict__ depth_out,       // (B,1) f32
    int B)
{
    const int lane = threadIdx.x & 63;
    const int widb = threadIdx.x >> 6;
    const int wpb  = blockDim.x >> 6;
    const int wave = blockIdx.x * wpb + widb;
    const int nwav = gridDim.x * wpb;

    for (int ray = wave; ray < B; ray += nwav) {
        const float* d = density + (size_t)ray * 128;
        const float* z = depth   + (size_t)ray * 128;
        const float* f = feature + (size_t)ray * 384;

        float za = z[lane];
        float zb = z[lane + 64];
        float da = d[lane];
        float db = d[lane + 64];

        // deltas: delta[i] = z[i+1]-z[i], delta[127] = FAR_DELTA
        float za_next = __shfl_down(za, 1);   // z[lane+1] for lane<63
        float zb0     = __shfl(zb, 0);        // z[64]
        if (lane == 63) za_next = zb0;
        float zb_next = __shfl_down(zb, 1);   // z[lane+65] for lane<63
        float delta_a = za_next - za;
        float delta_b = (lane == 63) ? FAR_DELTA : (zb_next - zb);

        float tau_a = da * delta_a;           // small (~1e-2)
        float tau_b = db * delta_b;           // small, except lane63: ~1e9-1e10
        float u_b   = (lane == 63) ? 0.0f : tau_b;  // scan-safe version

        // inclusive shuffle scans (all-small values, no cancellation)
        float sa = tau_a;
        #pragma unroll
        for (int off = 1; off < 64; off <<= 1) {
            float n = __shfl_up(sa, off);
            if (lane >= off) sa += n;
        }
        float sb = u_b;
        #pragma unroll
        for (int off = 1; off < 64; off <<= 1) {
            float n = __shfl_up(sb, off);
            if (lane >= off) sb += n;
        }
        float total_a = __shfl(sa, 63);       // sum of taus 0..63
        float cum_a = sa - tau_a;             // exclusive prefix, samples 0..63
        float cum_b = total_a + (sb - u_b);   // exclusive prefix, samples 64..127

        // weights = (1 - exp(-tau)) * exp(-cum); tau_b here is the REAL tau
        float w_a = -expm1f(-tau_a) * expf(-cum_a);
        float w_b = -expm1f(-tau_b) * expf(-cum_b);

        float r0 = w_a * f[lane * 3 + 0] + w_b * f[(lane + 64) * 3 + 0];
        float r1 = w_a * f[lane * 3 + 1] + w_b * f[(lane + 64) * 3 + 1];
        float r2 = w_a * f[lane * 3 + 2] + w_b * f[(lane + 64) * 3 + 2];
        float dp = w_a * za + w_b * zb;

        #pragma unroll
        for (int off = 32; off >= 1; off >>= 1) {
            r0 += __shfl_xor(r0, off);
            r1 += __shfl_xor(r1, off);
            r2 += __shfl_xor(r2, off);
            dp += __shfl_xor(dp, off);
        }

        if (lane == 0) {
            feat_out[(size_t)ray * 3 + 0] = r0;
            feat_out[(size_t)ray * 3 + 1] = r1;
            feat_out[(size_t)ray * 3 + 2] = r2;
            depth_out[ray] = dp;
        }
    }
}

extern "C" void kernel_launch(void* const* d_in, const int* in_sizes, int n_in,
                              void* d_out, int out_size, void* d_ws, size_t ws_size,
                              hipStream_t stream) {
    const float* density = (const float*)d_in[0];
    const float* feature = (const float*)d_in[1];
    const float* depth   = (const float*)d_in[2];
    const int N = 128;
    const int B = in_sizes[2] / N;                 // depth_values is (B,N)

    float* feat_out  = (float*)d_out;              // (B,3) flat f32
    float* depth_out = feat_out + (size_t)B * 3;   // (B,1) flat f32

    dim3 block(256);
    dim3 grid(2048);                               // 8192 waves, grid-stride
    hipLaunchKernelGGL(volrend_kernel, grid, block, 0, stream,
                       density, feature, depth, feat_out, depth_out, B);
}

// Round 7
// 64.446 us; speedup vs baseline: 1.1330x; 1.1330x over previous
//
#include <hip/hip_runtime.h>
#include <math.h>

#define FAR_DELTA 1e10f

// Half-wave per ray: lanes 0-31 own ray A, lanes 32-63 own ray B.
// Lane li (0..31) owns samples 4*li .. 4*li+3 of its ray.
// float4 loads for density/depth, 3x float4 for feature (all 16B-aligned,
// fully coalesced). Exclusive cumsum: 5-step guarded half-wave scan of
// per-lane tau sums (FAR tau excluded -> no cancellation). Transmittance
// by running product: one expf per sample + one per lane. Butterfly
// reduction (5 steps) handles both rays simultaneously.
__global__ __launch_bounds__(256) void volrend_kernel(
    const float* __restrict__ density,   // (B,128,1) f32
    const float* __restrict__ feature,   // (B,128,3) f32
    const float* __restrict__ depth,     // (B,128)   f32
    float* __restrict__ feat_out,        // (B,3) f32
    float* __restrict__ depth_out,       // (B,1) f32
    int B)
{
    const int lane = threadIdx.x & 63;
    const int li   = lane & 31;          // lane within half-wave
    const int half = lane >> 5;          // 0 = ray A, 1 = ray B
    const int widb = threadIdx.x >> 6;
    const int wpb  = blockDim.x >> 6;
    const int wave = blockIdx.x * wpb + widb;
    const int nwav = gridDim.x * wpb;
    const int npairs = B >> 1;           // B is even (131072)

    for (int p = wave; p < npairs; p += nwav) {
        const int ray = p * 2 + half;
        const size_t base = (size_t)ray * 128 + (size_t)li * 4;

        float4 dv = *reinterpret_cast<const float4*>(density + base);
        float4 zv = *reinterpret_cast<const float4*>(depth + base);
        const float4* fp = reinterpret_cast<const float4*>(feature + base * 3);
        float4 f0 = fp[0];               // r0 g0 b0 r1
        float4 f1 = fp[1];               // g1 b1 r2 g2
        float4 f2 = fp[2];               // b2 r3 g3 b3

        // deltas: 3 in-lane, 1 from next lane (FAR for last sample of ray)
        float zn = __shfl_down(zv.x, 1);
        float t0 = dv.x * (zv.y - zv.x);
        float t1 = dv.y * (zv.z - zv.y);
        float t2 = dv.z * (zv.w - zv.z);
        float t3 = dv.w * ((li == 31) ? FAR_DELTA : (zn - zv.w));

        // per-lane tau sum for the scan; exclude the huge FAR tau
        float lsum = t0 + t1 + t2 + ((li == 31) ? 0.0f : t3);

        // inclusive scan within each 32-lane half (guard blocks cross-half pulls)
        float s = lsum;
        #pragma unroll
        for (int off = 1; off < 32; off <<= 1) {
            float n = __shfl_up(s, off);
            if (li >= off) s += n;
        }
        float excl = s - lsum;           // sum of taus before sample 4*li

        // running transmittance: w_j = T * (1 - e_j); T *= e_j
        float T  = expf(-excl);
        float e0 = expf(-t0), e1 = expf(-t1), e2 = expf(-t2), e3 = expf(-t3);
        float w0 = T * (1.0f - e0); T *= e0;
        float w1 = T * (1.0f - e1); T *= e1;
        float w2 = T * (1.0f - e2); T *= e2;
        float w3 = T * (1.0f - e3);      // last sample of ray: e3=0 -> w3=T

        float r = w0 * f0.x + w1 * f0.w + w2 * f1.z + w3 * f2.y;
        float g = w0 * f0.y + w1 * f1.x + w2 * f1.w + w3 * f2.z;
        float b = w0 * f0.z + w1 * f1.y + w2 * f2.x + w3 * f2.w;
        float dz = w0 * zv.x + w1 * zv.y + w2 * zv.z + w3 * zv.w;

        // butterfly over each half (xor of bits 0..4 never crosses halves)
        #pragma unroll
        for (int off = 16; off >= 1; off >>= 1) {
            r  += __shfl_xor(r,  off);
            g  += __shfl_xor(g,  off);
            b  += __shfl_xor(b,  off);
            dz += __shfl_xor(dz, off);
        }

        if (li == 0) {                   // lanes 0 and 32 write their rays
            feat_out[(size_t)ray * 3 + 0] = r;
            feat_out[(size_t)ray * 3 + 1] = g;
            feat_out[(size_t)ray * 3 + 2] = b;
            depth_out[ray] = dz;
        }
    }
}

extern "C" void kernel_launch(void* const* d_in, const int* in_sizes, int n_in,
                              void* d_out, int out_size, void* d_ws, size_t ws_size,
                              hipStream_t stream) {
    const float* density = (const float*)d_in[0];
    const float* feature = (const float*)d_in[1];
    const float* depth   = (const float*)d_in[2];
    const int N = 128;
    const int B = in_sizes[2] / N;                 // depth_values is (B,N)

    float* feat_out  = (float*)d_out;              // (B,3) flat f32
    float* depth_out = feat_out + (size_t)B * 3;   // (B,1) flat f32

    dim3 block(256);
    dim3 grid(2048);                               // 8192 waves, 2 rays per wave-iter
    hipLaunchKernelGGL(volrend_kernel, grid, block, 0, stream,
                       density, feature, depth, feat_out, depth_out, B);
}

// Round 8
// 59.979 us; speedup vs baseline: 1.2174x; 1.0745x over previous
//
#include <hip/hip_runtime.h>
#include <math.h>

#define FAR_DELTA 1e10f

// Half-wave per ray: lanes 0-31 own ray A, lanes 32-63 own ray B.
// ONE ray-pair per wave (no grid-stride loop): 65536 independent waves keep
// the CUs saturated with fresh work so memory latency is hidden by wave
// turnover instead of in-wave pipelining.
// Lane li (0..31) owns samples 4*li .. 4*li+3 of its ray.
// float4 loads for density/depth, 3x float4 for feature (16B-aligned,
// fully coalesced). Exclusive cumsum: 5-step guarded half-wave scan of
// per-lane tau sums (FAR tau excluded -> no cancellation). Transmittance
// by running product: __expf per sample + one per lane.
__global__ __launch_bounds__(256, 8) void volrend_kernel(
    const float* __restrict__ density,   // (B,128,1) f32
    const float* __restrict__ feature,   // (B,128,3) f32
    const float* __restrict__ depth,     // (B,128)   f32
    float* __restrict__ feat_out,        // (B,3) f32
    float* __restrict__ depth_out,       // (B,1) f32
    int B)
{
    const int lane = threadIdx.x & 63;
    const int li   = lane & 31;          // lane within half-wave
    const int half = lane >> 5;          // 0 = ray A, 1 = ray B
    const int widb = threadIdx.x >> 6;
    const int wpb  = blockDim.x >> 6;
    const int p    = blockIdx.x * wpb + widb;   // one pair per wave
    const int npairs = B >> 1;
    if (p >= npairs) return;

    const int ray = p * 2 + half;
    const size_t base = (size_t)ray * 128 + (size_t)li * 4;

    float4 dv = *reinterpret_cast<const float4*>(density + base);
    float4 zv = *reinterpret_cast<const float4*>(depth + base);
    const float4* fp = reinterpret_cast<const float4*>(feature + base * 3);
    float4 f0 = fp[0];               // r0 g0 b0 r1
    float4 f1 = fp[1];               // g1 b1 r2 g2
    float4 f2 = fp[2];               // b2 r3 g3 b3

    // deltas: 3 in-lane, 1 from next lane (FAR for last sample of ray)
    float zn = __shfl_down(zv.x, 1);
    float t0 = dv.x * (zv.y - zv.x);
    float t1 = dv.y * (zv.z - zv.y);
    float t2 = dv.z * (zv.w - zv.z);
    float t3 = dv.w * ((li == 31) ? FAR_DELTA : (zn - zv.w));

    // per-lane tau sum for the scan; exclude the huge FAR tau
    float lsum = t0 + t1 + t2 + ((li == 31) ? 0.0f : t3);

    // inclusive scan within each 32-lane half (guard blocks cross-half pulls)
    float s = lsum;
    #pragma unroll
    for (int off = 1; off < 32; off <<= 1) {
        float n = __shfl_up(s, off);
        if (li >= off) s += n;
    }
    float excl = s - lsum;           // sum of taus before sample 4*li

    // running transmittance: w_j = T * (1 - e_j); T *= e_j
    float T  = __expf(-excl);
    float e0 = __expf(-t0), e1 = __expf(-t1), e2 = __expf(-t2), e3 = __expf(-t3);
    float w0 = T * (1.0f - e0); T *= e0;
    float w1 = T * (1.0f - e1); T *= e1;
    float w2 = T * (1.0f - e2); T *= e2;
    float w3 = T * (1.0f - e3);      // last sample of ray: e3=0 -> w3=T

    float r = w0 * f0.x + w1 * f0.w + w2 * f1.z + w3 * f2.y;
    float g = w0 * f0.y + w1 * f1.x + w2 * f1.w + w3 * f2.z;
    float b = w0 * f0.z + w1 * f1.y + w2 * f2.x + w3 * f2.w;
    float dz = w0 * zv.x + w1 * zv.y + w2 * zv.z + w3 * zv.w;

    // butterfly over each half (xor of bits 0..4 never crosses halves)
    #pragma unroll
    for (int off = 16; off >= 1; off >>= 1) {
        r  += __shfl_xor(r,  off);
        g  += __shfl_xor(g,  off);
        b  += __shfl_xor(b,  off);
        dz += __shfl_xor(dz, off);
    }

    if (li == 0) {                   // lanes 0 and 32 write their rays
        feat_out[(size_t)ray * 3 + 0] = r;
        feat_out[(size_t)ray * 3 + 1] = g;
        feat_out[(size_t)ray * 3 + 2] = b;
        depth_out[ray] = dz;
    }
}

extern "C" void kernel_launch(void* const* d_in, const int* in_sizes, int n_in,
                              void* d_out, int out_size, void* d_ws, size_t ws_size,
                              hipStream_t stream) {
    const float* density = (const float*)d_in[0];
    const float* feature = (const float*)d_in[1];
    const float* depth   = (const float*)d_in[2];
    const int N = 128;
    const int B = in_sizes[2] / N;                 // depth_values is (B,N)

    float* feat_out  = (float*)d_out;              // (B,3) flat f32
    float* depth_out = feat_out + (size_t)B * 3;   // (B,1) flat f32

    const int npairs = B >> 1;                     // 65536
    const int wavesPerBlock = 4;                   // 256 threads
    dim3 block(256);
    dim3 grid((npairs + wavesPerBlock - 1) / wavesPerBlock);  // 16384 blocks
    hipLaunchKernelGGL(volrend_kernel, grid, block, 0, stream,
                       density, feature, depth, feat_out, depth_out, B);
}